// Round 1
// baseline (310.795 us; speedup 1.0000x reference)
//
#include <hip/hip_runtime.h>

// SolventAccessibility: scatter-reduce atoms into (BATCH,NCHAIN,SEQ,NALT) bins,
// then normalize per-bin by residue-type min/max.
//
// Constants from the reference:
#define PADV   (-999)
#define BATCH  8
#define NCHAIN 2
#define SEQL   1024
#define NALT   3
#define NRES   20
#define NATOMS 2000000
#define GLY    7
#define NBINS  (BATCH * NCHAIN * SEQL * NALT)   // 49152

// ---------------------------------------------------------------------------
// Kernel 1: init accumulators (d_out) to 0, seq to PAD, and detect the
// device layout of `alternatives` (1-byte bool vs int32).
// Detection: int32 little-endian 0/1 values have byte==0 at positions
// !=0 (mod 4). np.bool_ layout has ~70% nonzero bytes everywhere.
// ---------------------------------------------------------------------------
__global__ void k_init(float* __restrict__ out /* 2*NBINS accumulators */,
                       int* __restrict__ seq,
                       int* __restrict__ flag,
                       const unsigned char* __restrict__ altBytes) {
    int i = blockIdx.x * blockDim.x + threadIdx.x;
    if (i < NBINS) {
        out[i]         = 0.0f;   // rsaMC accumulator
        out[NBINS + i] = 0.0f;   // rsaSC accumulator
        seq[i]         = PADV;
    }
    // Layout detection: wave 0 of block 0 samples bytes at 4k+1.
    if (blockIdx.x == 0 && threadIdx.x < 64) {
        unsigned char b = altBytes[threadIdx.x * 4 + 1];
        unsigned long long m = __ballot(b != 0);
        if (threadIdx.x == 0) {
            *flag = (m != 0ULL) ? 1 : 0;   // 1 = byte (np.bool_) layout, 0 = int32
        }
    }
}

// ---------------------------------------------------------------------------
// Kernel 2: per-atom scatter. One thread per atom, 3 alternatives each.
// ---------------------------------------------------------------------------
__global__ void k_scatter(const float* __restrict__ contRat,   // [NATOMS][NALT]
                          const int* __restrict__ desc,        // [NATOMS][5]
                          const unsigned char* __restrict__ altB,
                          const int* __restrict__ altI,
                          const int* __restrict__ flag,
                          float* __restrict__ rsaMC,
                          float* __restrict__ rsaSC,
                          int* __restrict__ seq) {
    int a = blockIdx.x * blockDim.x + threadIdx.x;
    if (a >= NATOMS) return;

    const int atname  = desc[a * 5 + 0];
    const int resnum  = desc[a * 5 + 1];
    const int chain   = desc[a * 5 + 2];
    const int batchI  = desc[a * 5 + 3];
    const int resname = desc[a * 5 + 4];

    const bool valid = (atname != PADV);
    const bool is_bb = (atname >= 0) && (atname <= 3);   // BACKBONE = {0,1,2,3}
    const int  base  = ((batchI * NCHAIN + chain) * SEQL + resnum) * NALT;

    const bool byteLayout = (*flag != 0);   // uniform scalar branch

    #pragma unroll
    for (int alt = 0; alt < NALT; ++alt) {
        bool altv;
        if (byteLayout) altv = (altB[a * NALT + alt] != 0);
        else            altv = (altI[a * NALT + alt] != 0);
        if (altv && valid) {
            const float c = contRat[a * NALT + alt];
            const int   f = base + alt;
            if (is_bb) {
                atomicAdd(&rsaMC[f], c);
                seq[f] = resname;   // all writers to f share resid -> same resname
            } else {
                atomicAdd(&rsaSC[f], c);
            }
        }
    }
}

// ---------------------------------------------------------------------------
// Kernel 3: normalize + clip, in place on d_out.
// ---------------------------------------------------------------------------
__global__ void k_final(float* __restrict__ mc,        // d_out[0 .. NBINS)
                        float* __restrict__ sc,        // d_out[NBINS .. 2*NBINS)
                        const int* __restrict__ seq,
                        const float* __restrict__ mcmax,
                        const float* __restrict__ mcmin,
                        const float* __restrict__ scmax,
                        const float* __restrict__ scmin) {
    int i = blockIdx.x * blockDim.x + threadIdx.x;
    if (i >= NBINS) return;

    const int s = seq[i];
    float m = mc[i];
    float v = sc[i];
    if (s != PADV) {
        int idx = s < 0 ? 0 : (s > NRES - 1 ? NRES - 1 : s);
        m = (m - mcmin[idx]) / (mcmax[idx] - mcmin[idx]);
        if (s != GLY) v = (v - scmin[idx]) / (scmax[idx] - scmin[idx]);
        else          v = 0.0f;
    }
    mc[i] = fminf(fmaxf(m, 0.0f), 1.0f);
    sc[i] = fminf(fmaxf(v, 0.0f), 1.0f);
}

// ---------------------------------------------------------------------------
extern "C" void kernel_launch(void* const* d_in, const int* in_sizes, int n_in,
                              void* d_out, int out_size, void* d_ws, size_t ws_size,
                              hipStream_t stream) {
    const float* contRat = (const float*)d_in[0];
    const float* mcmax   = (const float*)d_in[1];
    const float* mcmin   = (const float*)d_in[2];
    const float* scmax   = (const float*)d_in[3];
    const float* scmin   = (const float*)d_in[4];
    const int*   desc    = (const int*)d_in[5];
    const void*  alts    = d_in[6];

    float* out  = (float*)d_out;          // [0,NBINS)=rsaMC acc, [NBINS,2N)=rsaSC acc
    int*   seq  = (int*)d_ws;             // NBINS ints
    int*   flag = seq + NBINS;            // 1 int

    k_init<<<(NBINS + 255) / 256, 256, 0, stream>>>(
        out, seq, flag, (const unsigned char*)alts);

    k_scatter<<<(NATOMS + 255) / 256, 256, 0, stream>>>(
        contRat, desc,
        (const unsigned char*)alts, (const int*)alts, flag,
        out, out + NBINS, seq);

    k_final<<<(NBINS + 255) / 256, 256, 0, stream>>>(
        out, out + NBINS, seq, mcmax, mcmin, scmax, scmin);
}